// Round 9
// baseline (118.966 us; speedup 1.0000x reference)
//
#include <hip/hip_runtime.h>

#define NN 50000
#define NE 800000
#define D 64
#define BN_SH 8
#define BNODES 256
#define NB ((NN + BNODES - 1) / BNODES)     // 196 buckets
#define EPB 4096
#define NWB ((NE + EPB - 1) / EPB)          // 196 edge-chunk blocks
#define CONV_B 800                          // feat->bf16 convert blocks

// ---- workspace layout (~29 MB) ----
constexpr size_t alignup(size_t x) { return (x + 1023) & ~size_t(1023); }
constexpr size_t OFF_EM   = 0;                                        // NE*8   = 6.4 MB
constexpr size_t OFF_EM2  = alignup(OFF_EM + (size_t)NE * 8);         // NE*4   = 3.2 MB
constexpr size_t OFF_AGG  = alignup(OFF_EM2 + (size_t)NE * 4);        // bf16 agg (uses half)
constexpr size_t OFF_FB   = alignup(OFF_AGG + (size_t)NN * D * 4);    // NN*D*2 = 6.4 MB
constexpr size_t OFF_RS   = alignup(OFF_FB + (size_t)NN * D * 2);     // (NN+1) i32
constexpr size_t OFF_CNT  = alignup(OFF_RS + (size_t)(NN + 1) * 4);   // NWB*NB i32 = 154 KB
constexpr size_t OFF_BASE = alignup(OFF_CNT + (size_t)NWB * NB * 4);  // NB+1 i32

__device__ __forceinline__ unsigned f2bf(unsigned u) {   // f32 bits -> bf16 bits, RNE
    return (u + 0x7FFFu + ((u >> 16) & 1u)) >> 16;
}

// K1: blocks [0,NWB): per-chunk bucket histogram -> cnt[blk][b] (deterministic,
//     row-private writes). blocks [NWB, NWB+CONV_B): feat -> bf16 convert.
__global__ __launch_bounds__(256) void prep(const int* __restrict__ dst,
                                            const float* __restrict__ feat,
                                            int* __restrict__ cnt,
                                            ushort* __restrict__ fb16) {
    int b = blockIdx.x;
    if (b < NWB) {
        __shared__ int h[NB];
        for (int i = threadIdx.x; i < NB; i += 256) h[i] = 0;
        __syncthreads();
        int c0 = b * EPB;
        int lim = min(EPB, NE - c0);
        for (int j = threadIdx.x; j < lim; j += 256)
            atomicAdd(&h[dst[c0 + j] >> BN_SH], 1);
        __syncthreads();
        for (int i = threadIdx.x; i < NB; i += 256) cnt[b * NB + i] = h[i];
    } else {
        int cb = b - NWB;
        const float4* f4 = (const float4*)feat;
        ushort4* o4 = (ushort4*)fb16;
        for (int i = cb * 256 + threadIdx.x; i < NN * D / 4; i += CONV_B * 256) {
            float4 v = f4[i];
            ushort4 o;
            o.x = (ushort)f2bf(__float_as_uint(v.x));
            o.y = (ushort)f2bf(__float_as_uint(v.y));
            o.z = (ushort)f2bf(__float_as_uint(v.z));
            o.w = (ushort)f2bf(__float_as_uint(v.w));
            o4[i] = o;
        }
    }
}

// K2: single block. Bucket totals from cnt columns -> exclusive bases; then
// rewrite cnt[blk][b] in-place as the per-(block,bucket) write base.
__global__ __launch_bounds__(256) void scanw(int* __restrict__ cnt,
                                             int* __restrict__ base,
                                             int* __restrict__ rs) {
    __shared__ int sh[256];
    int t = threadIdx.x;
    int total = 0;
    if (t < NB)
        for (int blk = 0; blk < NWB; ++blk) total += cnt[blk * NB + t];
    sh[t] = total;
    __syncthreads();
    for (int o = 1; o < 256; o <<= 1) {
        int x = (t >= o) ? sh[t - o] : 0;
        __syncthreads();
        sh[t] += x;
        __syncthreads();
    }
    int ex = sh[t] - total;
    if (t < NB) {
        base[t] = ex;
        int run = ex;
        for (int blk = 0; blk < NWB; ++blk) {
            int v = cnt[blk * NB + t];
            cnt[blk * NB + t] = run;
            run += v;
        }
    }
    if (t == 0) { base[NB] = NE; rs[NN] = NE; }
}

// K3: binned edge write, fully deterministic (bases precomputed, ranks via LDS).
// rec = { src | dst_local<<16 , bits(ew) }
__global__ __launch_bounds__(256) void bin_write(const int* __restrict__ src,
                                                 const int* __restrict__ dst,
                                                 const float* __restrict__ ew,
                                                 const int* __restrict__ cnt,
                                                 uint2* __restrict__ em) {
    __shared__ int h[NB];
    __shared__ int gb[NB];
    for (int i = threadIdx.x; i < NB; i += 256) h[i] = 0;
    __syncthreads();
    int c0 = blockIdx.x * EPB;
    uint2 rec[16];
    int rk[16];
    int bk[16];
#pragma unroll
    for (int j = 0; j < 16; ++j) {
        int e = c0 + j * 256 + threadIdx.x;
        if (e < NE) {
            int dv = dst[e];
            int b = dv >> BN_SH;
            bk[j] = b;
            rk[j] = atomicAdd(&h[b], 1);
            rec[j] = make_uint2((unsigned)src[e] | ((unsigned)(dv & (BNODES - 1)) << 16),
                                __float_as_uint(ew[e]));
        } else bk[j] = -1;
    }
    __syncthreads();
    for (int i = threadIdx.x; i < NB; i += 256) gb[i] = cnt[blockIdx.x * NB + i];
    __syncthreads();
#pragma unroll
    for (int j = 0; j < 16; ++j)
        if (bk[j] >= 0) em[gb[bk[j]] + rk[j]] = rec[j];
}

// K4: per-bucket counting sort -> exact per-node CSR; em2 packed to 4 B:
// { src:16 | bf16(w):16 }  (dst_local no longer needed after the sort).
__global__ __launch_bounds__(256) void bucket_csr(const uint2* __restrict__ em,
                                                  const int* __restrict__ base,
                                                  int* __restrict__ rs,
                                                  unsigned* __restrict__ em2) {
    __shared__ int hist[BNODES];
    __shared__ int lbase[BNODES];
    __shared__ int lcur[BNODES];
    __shared__ int sh[BNODES];
    int b = blockIdx.x;
    int t = threadIdx.x;
    int beg = base[b], end = base[b + 1];
    hist[t] = 0;
    __syncthreads();
    for (int e = beg + t; e < end; e += 256)
        atomicAdd(&hist[(em[e].x >> 16) & 0xFFu], 1);
    __syncthreads();
    int v = hist[t];
    sh[t] = v;
    __syncthreads();
    for (int o = 1; o < 256; o <<= 1) {
        int x = (t >= o) ? sh[t - o] : 0;
        __syncthreads();
        sh[t] += x;
        __syncthreads();
    }
    int ex = sh[t] - v;
    lbase[t] = ex;
    lcur[t] = 0;
    int n = (b << BN_SH) + t;
    if (n < NN) rs[n] = beg + ex;
    __syncthreads();
    for (int e = beg + t; e < end; e += 256) {
        uint2 r = em[e];
        unsigned dl = (r.x >> 16) & 0xFFu;
        int pos = beg + lbase[dl] + atomicAdd(&lcur[dl], 1);
        em2[pos] = (r.x & 0xFFFFu) | (f2bf(r.y) << 16);
    }
}

// K5: gather — TWO waves per node (halved serial latency chain), 4 nodes per
// 512-thread block. Deterministic split mid=(beg+end)>>1; LDS combine; bf16 out.
__global__ __launch_bounds__(512) void gc_gather(const ushort* __restrict__ fb16,
                                                 const int* __restrict__ rs,
                                                 const unsigned* __restrict__ em2,
                                                 ushort* __restrict__ aggb) {
    __shared__ float comb[4][64];
    int w = threadIdx.x >> 6;        // wave 0..7
    int lane = threadIdx.x & 63;
    int sub = w & 1;                 // which half of the run
    int nl = w >> 1;                 // local node 0..3
    int n = blockIdx.x * 4 + nl;
    bool valid = (n < NN);
    int beg = 0, end = 0;
    if (valid) {
        beg = __builtin_amdgcn_readfirstlane(rs[n]);
        end = __builtin_amdgcn_readfirstlane(rs[n + 1]);
    }
    int mid = (beg + end) >> 1;
    int lo = sub ? mid : beg;
    int hi = sub ? end : mid;
    float acc = 0.f;
    int e = lo;
    for (; e + 4 <= hi; e += 4) {
        unsigned v0 = em2[e], v1 = em2[e + 1], v2 = em2[e + 2], v3 = em2[e + 3];
        float f0 = __uint_as_float((unsigned)fb16[(size_t)(v0 & 0xFFFFu) * D + lane] << 16);
        float f1 = __uint_as_float((unsigned)fb16[(size_t)(v1 & 0xFFFFu) * D + lane] << 16);
        float f2 = __uint_as_float((unsigned)fb16[(size_t)(v2 & 0xFFFFu) * D + lane] << 16);
        float f3 = __uint_as_float((unsigned)fb16[(size_t)(v3 & 0xFFFFu) * D + lane] << 16);
        acc = fmaf(__uint_as_float(v0 & 0xFFFF0000u), f0, acc);
        acc = fmaf(__uint_as_float(v1 & 0xFFFF0000u), f1, acc);
        acc = fmaf(__uint_as_float(v2 & 0xFFFF0000u), f2, acc);
        acc = fmaf(__uint_as_float(v3 & 0xFFFF0000u), f3, acc);
    }
    for (; e < hi; ++e) {
        unsigned v = em2[e];
        float f = __uint_as_float((unsigned)fb16[(size_t)(v & 0xFFFFu) * D + lane] << 16);
        acc = fmaf(__uint_as_float(v & 0xFFFF0000u), f, acc);
    }
    if (sub == 0 && valid) comb[nl][lane] = acc;
    __syncthreads();
    if (sub == 1 && valid) {
        float s = comb[nl][lane] + acc;   // fixed order: first half + second half
        aggb[(size_t)n * D + lane] = (ushort)f2bf(__float_as_uint(s));
    }
}

// K6: epilogue GEMM: C[N,64] = [agg | feat] @ [Wn ; Ws^T] + bn.
// A-operands arrive bf16 (aggb, fb16), converted to f32 while staging to LDS;
// weights/bias stay f32. Inner loop identical to the proven round-6 version.
#define BM 128
__global__ __launch_bounds__(256) void gemm_out(const ushort* __restrict__ aggb,
                                                const ushort* __restrict__ fb16,
                                                const float* __restrict__ Wn,
                                                const float* __restrict__ Ws,
                                                const float* __restrict__ bn,
                                                float* __restrict__ out) {
    __shared__ float Bs[128 * 64];   // 32 KB: Bs[k*64+d]
    __shared__ float As[BM * 36];    // 18 KB, stride 36
    int tid = threadIdx.x;
    for (int i = tid; i < 128 * 64; i += 256) {
        int k = i >> 6, d = i & 63;
        Bs[i] = (k < 64) ? Wn[i] : Ws[d * 64 + (k - 64)];
    }
    int tn = tid & 7;
    int tm = tid >> 3;
    float4 blo = *(const float4*)&bn[tn * 8];
    float4 bhi = *(const float4*)&bn[tn * 8 + 4];
    float acc[4][8];
#pragma unroll
    for (int i = 0; i < 4; ++i) {
        acc[i][0] = blo.x; acc[i][1] = blo.y; acc[i][2] = blo.z; acc[i][3] = blo.w;
        acc[i][4] = bhi.x; acc[i][5] = bhi.y; acc[i][6] = bhi.z; acc[i][7] = bhi.w;
    }
    int n0 = blockIdx.x * BM;
    for (int c = 0; c < 4; ++c) {
        const ushort* Asrc = (c < 2) ? aggb : fb16;
        int ksrc = (c & 1) * 32;
        __syncthreads();
        for (int i = tid; i < BM * 8; i += 256) {
            int r = i >> 3, c4 = i & 7;
            int nrow = n0 + r;
            const ushort* p = Asrc + (size_t)(nrow < NN ? nrow : 0) * 64 + ksrc + c4 * 4;
            ushort4 v = *(const ushort4*)p;
            float* q = &As[r * 36 + c4 * 4];
            q[0] = __uint_as_float((unsigned)v.x << 16);
            q[1] = __uint_as_float((unsigned)v.y << 16);
            q[2] = __uint_as_float((unsigned)v.z << 16);
            q[3] = __uint_as_float((unsigned)v.w << 16);
        }
        __syncthreads();
        int kb = c * 32;
#pragma unroll
        for (int k4 = 0; k4 < 8; ++k4) {
            float4 av[4];
#pragma unroll
            for (int i = 0; i < 4; ++i)
                av[i] = *(const float4*)&As[(tm + 32 * i) * 36 + k4 * 4];
#pragma unroll
            for (int kk = 0; kk < 4; ++kk) {
                int k = kb + k4 * 4 + kk;
                float4 wlo = *(const float4*)&Bs[k * 64 + tn * 8];
                float4 whi = *(const float4*)&Bs[k * 64 + tn * 8 + 4];
#pragma unroll
                for (int i = 0; i < 4; ++i) {
                    float a = (kk == 0) ? av[i].x : (kk == 1) ? av[i].y
                            : (kk == 2) ? av[i].z : av[i].w;
                    acc[i][0] = fmaf(a, wlo.x, acc[i][0]);
                    acc[i][1] = fmaf(a, wlo.y, acc[i][1]);
                    acc[i][2] = fmaf(a, wlo.z, acc[i][2]);
                    acc[i][3] = fmaf(a, wlo.w, acc[i][3]);
                    acc[i][4] = fmaf(a, whi.x, acc[i][4]);
                    acc[i][5] = fmaf(a, whi.y, acc[i][5]);
                    acc[i][6] = fmaf(a, whi.z, acc[i][6]);
                    acc[i][7] = fmaf(a, whi.w, acc[i][7]);
                }
            }
        }
    }
#pragma unroll
    for (int i = 0; i < 4; ++i) {
        int r = n0 + tm + 32 * i;
        if (r < NN) {
            float* p = &out[(size_t)r * 64 + tn * 8];
            *(float4*)p = make_float4(acc[i][0], acc[i][1], acc[i][2], acc[i][3]);
            *(float4*)(p + 4) = make_float4(acc[i][4], acc[i][5], acc[i][6], acc[i][7]);
        }
    }
}

extern "C" void kernel_launch(void* const* d_in, const int* in_sizes, int n_in,
                              void* d_out, int out_size, void* d_ws, size_t ws_size,
                              hipStream_t stream) {
    const float* feat = (const float*)d_in[0];
    const int*   src  = (const int*)d_in[1];
    const int*   dst  = (const int*)d_in[2];
    const float* ew   = (const float*)d_in[3];
    const float* Wn   = (const float*)d_in[4];
    const float* bn   = (const float*)d_in[5];
    const float* Ws   = (const float*)d_in[6];
    float* out = (float*)d_out;

    char* ws = (char*)d_ws;
    uint2*    em   = (uint2*)(ws + OFF_EM);
    unsigned* em2  = (unsigned*)(ws + OFF_EM2);
    ushort*   aggb = (ushort*)(ws + OFF_AGG);
    ushort*   fb16 = (ushort*)(ws + OFF_FB);
    int*      rs   = (int*)(ws + OFF_RS);
    int*      cnt  = (int*)(ws + OFF_CNT);
    int*      base = (int*)(ws + OFF_BASE);

    prep<<<NWB + CONV_B, 256, 0, stream>>>(dst, feat, cnt, fb16);
    scanw<<<1, 256, 0, stream>>>(cnt, base, rs);
    bin_write<<<NWB, 256, 0, stream>>>(src, dst, ew, cnt, em);
    bucket_csr<<<NB, 256, 0, stream>>>(em, base, rs, em2);
    gc_gather<<<(NN + 3) / 4, 512, 0, stream>>>(fb16, rs, em2, aggb);
    gemm_out<<<(NN + BM - 1) / BM, 256, 0, stream>>>(aggb, fb16, Wn, Ws, bn, out);
}

// Round 10
// 84.503 us; speedup vs baseline: 1.4078x; 1.4078x over previous
//
#include <hip/hip_runtime.h>

#define NN 50000
#define NE 800000
#define D 64
#define BN_SH 8
#define BNODES 256
#define NB 196                              // buckets of 256 dst nodes
#define EPB 4096
#define NWB 196                             // edge-chunk blocks (196*4096 >= NE)
#define CONV_B 800                          // feat->bf16 convert blocks
#define BCAP 4608                           // per-bucket region capacity (mean 4081 + 8 sigma)

// ---- workspace layout (~31 MB) ----
constexpr size_t alignup(size_t x) { return (x + 1023) & ~size_t(1023); }
constexpr size_t OFF_EM   = 0;                                         // NB*BCAP*8 = 7.2 MB
constexpr size_t OFF_EM2  = alignup(OFF_EM + (size_t)NB * BCAP * 8);   // NB*BCAP*4 = 3.6 MB
constexpr size_t OFF_AGG  = alignup(OFF_EM2 + (size_t)NB * BCAP * 4);  // NN*D*4 = 12.8 MB
constexpr size_t OFF_FB   = alignup(OFF_AGG + (size_t)NN * D * 4);     // NN*D*2 = 6.4 MB
constexpr size_t OFF_RS2  = alignup(OFF_FB + (size_t)NN * D * 2);      // NN int2 = 400 KB
constexpr size_t OFF_CUR  = alignup(OFF_RS2 + (size_t)NN * 8);         // NB i32

__device__ __forceinline__ unsigned f2bf(unsigned u) {   // f32 bits -> bf16 bits, RNE
    return (u + 0x7FFFu + ((u >> 16) & 1u)) >> 16;
}

// K0: zero bucket cursors
__global__ __launch_bounds__(256) void gc_zero(int* cur) {
    if (threadIdx.x < NB) cur[threadIdx.x] = 0;
}

// K1: blocks [0,NWB): binned edge write into fixed per-bucket regions with
// per-block bulk atomic reservation (196 LDS-aggregated atomics per block).
// blocks [NWB, NWB+CONV_B): feat -> bf16 convert.
// rec = { src | dst_local<<16 , bits(ew) }
__global__ __launch_bounds__(256) void bin_write(const int* __restrict__ src,
                                                 const int* __restrict__ dst,
                                                 const float* __restrict__ ew,
                                                 const float* __restrict__ feat,
                                                 int* __restrict__ cur,
                                                 uint2* __restrict__ em,
                                                 ushort* __restrict__ fb16) {
    int b = blockIdx.x;
    if (b >= NWB) {
        int cb = b - NWB;
        const float4* f4 = (const float4*)feat;
        ushort4* o4 = (ushort4*)fb16;
        for (int i = cb * 256 + threadIdx.x; i < NN * D / 4; i += CONV_B * 256) {
            float4 v = f4[i];
            ushort4 o;
            o.x = (ushort)f2bf(__float_as_uint(v.x));
            o.y = (ushort)f2bf(__float_as_uint(v.y));
            o.z = (ushort)f2bf(__float_as_uint(v.z));
            o.w = (ushort)f2bf(__float_as_uint(v.w));
            o4[i] = o;
        }
        return;
    }
    __shared__ int h[NB];
    __shared__ int gb[NB];
    for (int i = threadIdx.x; i < NB; i += 256) h[i] = 0;
    __syncthreads();
    int c0 = b * EPB;
    uint2 rec[16];
    int rk[16];
    int bk[16];
#pragma unroll
    for (int j = 0; j < 16; ++j) {
        int e = c0 + j * 256 + threadIdx.x;
        if (e < NE) {
            int dv = dst[e];
            int bb = dv >> BN_SH;
            bk[j] = bb;
            rk[j] = atomicAdd(&h[bb], 1);
            rec[j] = make_uint2((unsigned)src[e] | ((unsigned)(dv & (BNODES - 1)) << 16),
                                __float_as_uint(ew[e]));
        } else bk[j] = -1;
    }
    __syncthreads();
    for (int i = threadIdx.x; i < NB; i += 256) {
        int c = h[i];
        gb[i] = c ? atomicAdd(&cur[i], c) : 0;
    }
    __syncthreads();
#pragma unroll
    for (int j = 0; j < 16; ++j)
        if (bk[j] >= 0)
            em[(size_t)bk[j] * BCAP + gb[bk[j]] + rk[j]] = rec[j];
}

// K2: per-bucket counting sort -> per-node {beg,end} runs (rs2); em2 packed
// to 4 B: { src:16 | bf16(w):16 }. All writes stay in the block's own region.
__global__ __launch_bounds__(256) void bucket_csr(const uint2* __restrict__ em,
                                                  const int* __restrict__ cur,
                                                  int2* __restrict__ rs2,
                                                  unsigned* __restrict__ em2) {
    __shared__ int hist[BNODES];
    __shared__ int lbase[BNODES];
    __shared__ int lcur[BNODES];
    __shared__ int sh[BNODES];
    int b = blockIdx.x;
    int t = threadIdx.x;
    int beg = b * BCAP;
    int end = beg + cur[b];
    hist[t] = 0;
    __syncthreads();
    for (int e = beg + t; e < end; e += 256)
        atomicAdd(&hist[(em[e].x >> 16) & 0xFFu], 1);
    __syncthreads();
    int v = hist[t];
    sh[t] = v;
    __syncthreads();
    for (int o = 1; o < 256; o <<= 1) {
        int x = (t >= o) ? sh[t - o] : 0;
        __syncthreads();
        sh[t] += x;
        __syncthreads();
    }
    int ex = sh[t] - v;
    lbase[t] = ex;
    lcur[t] = 0;
    int n = (b << BN_SH) + t;
    if (n < NN) rs2[n] = make_int2(beg + ex, beg + ex + v);
    __syncthreads();
    for (int e = beg + t; e < end; e += 256) {
        uint2 r = em[e];
        unsigned dl = (r.x >> 16) & 0xFFu;
        int pos = beg + lbase[dl] + atomicAdd(&lcur[dl], 1);
        em2[pos] = (r.x & 0xFFFFu) | (f2bf(r.y) << 16);
    }
}

// K3: gather — ONE wave per node, 8-deep unrolled edge loop (8 row-gathers in
// flight per wave; consecutive wave-uniform em2 reads coalesce to scalar loads).
__global__ __launch_bounds__(256) void gc_gather(const ushort* __restrict__ fb16,
                                                 const int2* __restrict__ rs2,
                                                 const unsigned* __restrict__ em2,
                                                 float* __restrict__ agg) {
    int wid = threadIdx.x >> 6;
    int lane = threadIdx.x & 63;
    int n = blockIdx.x * 4 + wid;
    if (n >= NN) return;
    int2 r2 = rs2[n];
    int beg = __builtin_amdgcn_readfirstlane(r2.x);
    int end = __builtin_amdgcn_readfirstlane(r2.y);
    float acc = 0.f;
    int e = beg;
    for (; e + 8 <= end; e += 8) {
        unsigned v[8];
#pragma unroll
        for (int j = 0; j < 8; ++j) v[j] = em2[e + j];
        float f[8];
#pragma unroll
        for (int j = 0; j < 8; ++j)
            f[j] = __uint_as_float((unsigned)fb16[(size_t)(v[j] & 0xFFFFu) * D + lane] << 16);
#pragma unroll
        for (int j = 0; j < 8; ++j)
            acc = fmaf(__uint_as_float(v[j] & 0xFFFF0000u), f[j], acc);
    }
    for (; e + 4 <= end; e += 4) {
        unsigned v0 = em2[e], v1 = em2[e + 1], v2 = em2[e + 2], v3 = em2[e + 3];
        float f0 = __uint_as_float((unsigned)fb16[(size_t)(v0 & 0xFFFFu) * D + lane] << 16);
        float f1 = __uint_as_float((unsigned)fb16[(size_t)(v1 & 0xFFFFu) * D + lane] << 16);
        float f2 = __uint_as_float((unsigned)fb16[(size_t)(v2 & 0xFFFFu) * D + lane] << 16);
        float f3 = __uint_as_float((unsigned)fb16[(size_t)(v3 & 0xFFFFu) * D + lane] << 16);
        acc = fmaf(__uint_as_float(v0 & 0xFFFF0000u), f0, acc);
        acc = fmaf(__uint_as_float(v1 & 0xFFFF0000u), f1, acc);
        acc = fmaf(__uint_as_float(v2 & 0xFFFF0000u), f2, acc);
        acc = fmaf(__uint_as_float(v3 & 0xFFFF0000u), f3, acc);
    }
    for (; e < end; ++e) {
        unsigned v = em2[e];
        float f = __uint_as_float((unsigned)fb16[(size_t)(v & 0xFFFFu) * D + lane] << 16);
        acc = fmaf(__uint_as_float(v & 0xFFFF0000u), f, acc);
    }
    agg[(size_t)n * D + lane] = acc;
}

// K4: epilogue GEMM (identical to the round-8 known-good version):
// C[N,64] = [agg | feat] @ [Wn ; Ws^T] + bn.
#define BM 128
__global__ __launch_bounds__(256) void gemm_out(const float* __restrict__ agg,
                                                const float* __restrict__ feat,
                                                const float* __restrict__ Wn,
                                                const float* __restrict__ Ws,
                                                const float* __restrict__ bn,
                                                float* __restrict__ out) {
    __shared__ float Bs[128 * 64];   // 32 KB: Bs[k*64+d]
    __shared__ float As[BM * 36];    // 18 KB, stride 36
    int tid = threadIdx.x;
    for (int i = tid; i < 128 * 64; i += 256) {
        int k = i >> 6, d = i & 63;
        Bs[i] = (k < 64) ? Wn[i] : Ws[d * 64 + (k - 64)];
    }
    int tn = tid & 7;
    int tm = tid >> 3;
    float4 blo = *(const float4*)&bn[tn * 8];
    float4 bhi = *(const float4*)&bn[tn * 8 + 4];
    float acc[4][8];
#pragma unroll
    for (int i = 0; i < 4; ++i) {
        acc[i][0] = blo.x; acc[i][1] = blo.y; acc[i][2] = blo.z; acc[i][3] = blo.w;
        acc[i][4] = bhi.x; acc[i][5] = bhi.y; acc[i][6] = bhi.z; acc[i][7] = bhi.w;
    }
    int n0 = blockIdx.x * BM;
    for (int c = 0; c < 4; ++c) {
        const float* Asrc = (c < 2) ? agg : feat;
        int ksrc = (c & 1) * 32;
        __syncthreads();
        for (int i = tid; i < BM * 8; i += 256) {
            int r = i >> 3, c4 = i & 7;
            int nrow = n0 + r;
            const float* p = Asrc + (size_t)(nrow < NN ? nrow : 0) * 64 + ksrc + c4 * 4;
            float4 v = *(const float4*)p;
            float* q = &As[r * 36 + c4 * 4];
            q[0] = v.x; q[1] = v.y; q[2] = v.z; q[3] = v.w;
        }
        __syncthreads();
        int kb = c * 32;
#pragma unroll
        for (int k4 = 0; k4 < 8; ++k4) {
            float4 av[4];
#pragma unroll
            for (int i = 0; i < 4; ++i)
                av[i] = *(const float4*)&As[(tm + 32 * i) * 36 + k4 * 4];
#pragma unroll
            for (int kk = 0; kk < 4; ++kk) {
                int k = kb + k4 * 4 + kk;
                float4 wlo = *(const float4*)&Bs[k * 64 + tn * 8];
                float4 whi = *(const float4*)&Bs[k * 64 + tn * 8 + 4];
#pragma unroll
                for (int i = 0; i < 4; ++i) {
                    float a = (kk == 0) ? av[i].x : (kk == 1) ? av[i].y
                            : (kk == 2) ? av[i].z : av[i].w;
                    acc[i][0] = fmaf(a, wlo.x, acc[i][0]);
                    acc[i][1] = fmaf(a, wlo.y, acc[i][1]);
                    acc[i][2] = fmaf(a, wlo.z, acc[i][2]);
                    acc[i][3] = fmaf(a, wlo.w, acc[i][3]);
                    acc[i][4] = fmaf(a, whi.x, acc[i][4]);
                    acc[i][5] = fmaf(a, whi.y, acc[i][5]);
                    acc[i][6] = fmaf(a, whi.z, acc[i][6]);
                    acc[i][7] = fmaf(a, whi.w, acc[i][7]);
                }
            }
        }
    }
#pragma unroll
    for (int i = 0; i < 4; ++i) {
        int r = n0 + tm + 32 * i;
        if (r < NN) {
            float* p = &out[(size_t)r * 64 + tn * 8];
            *(float4*)p = make_float4(acc[i][0], acc[i][1], acc[i][2], acc[i][3]);
            *(float4*)(p + 4) = make_float4(acc[i][4], acc[i][5], acc[i][6], acc[i][7]);
        }
    }
}

extern "C" void kernel_launch(void* const* d_in, const int* in_sizes, int n_in,
                              void* d_out, int out_size, void* d_ws, size_t ws_size,
                              hipStream_t stream) {
    const float* feat = (const float*)d_in[0];
    const int*   src  = (const int*)d_in[1];
    const int*   dst  = (const int*)d_in[2];
    const float* ew   = (const float*)d_in[3];
    const float* Wn   = (const float*)d_in[4];
    const float* bn   = (const float*)d_in[5];
    const float* Ws   = (const float*)d_in[6];
    float* out = (float*)d_out;

    char* ws = (char*)d_ws;
    uint2*    em   = (uint2*)(ws + OFF_EM);
    unsigned* em2  = (unsigned*)(ws + OFF_EM2);
    float*    agg  = (float*)(ws + OFF_AGG);
    ushort*   fb16 = (ushort*)(ws + OFF_FB);
    int2*     rs2  = (int2*)(ws + OFF_RS2);
    int*      cur  = (int*)(ws + OFF_CUR);

    gc_zero<<<1, 256, 0, stream>>>(cur);
    bin_write<<<NWB + CONV_B, 256, 0, stream>>>(src, dst, ew, feat, cur, em, fb16);
    bucket_csr<<<NB, 256, 0, stream>>>(em, cur, rs2, em2);
    gc_gather<<<(NN + 3) / 4, 256, 0, stream>>>(fb16, rs2, em2, agg);
    gemm_out<<<(NN + BM - 1) / BM, 256, 0, stream>>>(agg, feat, Wn, Ws, bn, out);
}